// Round 11
// baseline (640.297 us; speedup 1.0000x reference)
//
#include <hip/hip_runtime.h>
#include <stdint.h>
#include <math.h>

#define NN   8192
#define IND  256
#define HID  16
#define KN   6
#define SN   4        // col quarters (merge width)
#define QWID (NN/SN)  // cols per quarter = 2048
#define CCOL 256      // cols per LDS chunk
#define NCH  (QWID/CCOL)  // chunks per block = 8
#define TPC  (CCOL/16)    // tiles per chunk per wave = 16

typedef short s8v  __attribute__((ext_vector_type(8)));   // 8 bf16 in 4 VGPRs
typedef float f4v  __attribute__((ext_vector_type(4)));

__device__ __forceinline__ uint64_t kmax(uint64_t a, uint64_t b) { return a > b ? a : b; }
__device__ __forceinline__ uint64_t kmin(uint64_t a, uint64_t b) { return a < b ? a : b; }

__device__ __forceinline__ uint32_t fflip(float f) {
    const uint32_t u = __float_as_uint(f);
    return (u & 0x80000000u) ? ~u : (u | 0x80000000u);
}

// RNE float -> bf16 bits (top 16)
__device__ __forceinline__ uint32_t bf16_rne_bits(float x) {
    const uint32_t u = __float_as_uint(x);
    return (u + 0x7FFFu + ((u >> 16) & 1u)) & 0xFFFF0000u;
}

// ---------------------------------------------------------------------------
// k1: h[i] = normalize(x[i] @ W^T + b), also zero rs[i].
// ---------------------------------------------------------------------------
__global__ __launch_bounds__(256) void k1_embed(const float* __restrict__ x,
                                                const float* __restrict__ W,
                                                const float* __restrict__ b,
                                                float* __restrict__ h,
                                                float* __restrict__ rs)
{
    const int lane = threadIdx.x & 63;
    const int wv   = threadIdx.x >> 6;
    const int row  = blockIdx.x * 4 + wv;

    const float4 xv = *(const float4*)(x + (size_t)row * IND + lane * 4);

    float acc[HID];
#pragma unroll
    for (int k = 0; k < HID; ++k) {
        const float4 wv4 = *(const float4*)(W + (size_t)k * IND + lane * 4);
        float v = xv.x * wv4.x + xv.y * wv4.y + xv.z * wv4.z + xv.w * wv4.w;
#pragma unroll
        for (int m = 32; m >= 1; m >>= 1) v += __shfl_xor(v, m, 64);
        acc[k] = v;
    }

    if (lane == 0) {
        float hv[HID];
        float ss = 0.f;
#pragma unroll
        for (int k = 0; k < HID; ++k) { hv[k] = acc[k] + b[k]; ss += hv[k] * hv[k]; }
        const float nrm = fmaxf(sqrtf(ss), 1e-12f);
#pragma unroll
        for (int k = 0; k < HID; ++k) hv[k] = hv[k] / nrm;
        float4* hp = (float4*)(h + (size_t)row * HID);
        hp[0] = make_float4(hv[0],  hv[1],  hv[2],  hv[3]);
        hp[1] = make_float4(hv[4],  hv[5],  hv[6],  hv[7]);
        hp[2] = make_float4(hv[8],  hv[9],  hv[10], hv[11]);
        hp[3] = make_float4(hv[12], hv[13], hv[14], hv[15]);
        rs[row] = 0.f;
    }
}

// ---------------------------------------------------------------------------
// k1b: split h into 3 exact bf16 limbs; 5 K=32 packings (verified R8-R10):
// PA1=[hi|hi] PA2=[mid|hi] PA3=[lo|mid]  (stationary i / B operand)
// PB1=[hi|mid] PB2=[hi|lo]               (streamed j / A operand)
// mfma(PB1,PA1)+mfma(PB2,PA2)+mfma(PB1,PA3) = hh+mh+hm+lh+hl+mm (~6e-8 err).
// ---------------------------------------------------------------------------
__global__ __launch_bounds__(256) void k1b_split(const float* __restrict__ h,
                                                 ushort* __restrict__ PA1,
                                                 ushort* __restrict__ PA2,
                                                 ushort* __restrict__ PA3,
                                                 ushort* __restrict__ PB1,
                                                 ushort* __restrict__ PB2)
{
    const int t   = blockIdx.x * 256 + threadIdx.x;   // < NN*32
    const int row = t >> 5;
    const int s   = t & 31;
    const int k   = s & 15;

    const float x = h[(size_t)row * HID + k];
    const uint32_t hb = bf16_rne_bits(x);
    const float r1 = x - __uint_as_float(hb);
    const uint32_t mb = bf16_rne_bits(r1);
    const float r2 = r1 - __uint_as_float(mb);
    const uint32_t lb = bf16_rne_bits(r2);
    const ushort hi = (ushort)(hb >> 16);
    const ushort mi = (ushort)(mb >> 16);
    const ushort lo = (ushort)(lb >> 16);

    const bool f = (s < 16);
    PA1[t] = hi;
    PA2[t] = f ? mi : hi;
    PA3[t] = f ? lo : mi;
    PB1[t] = f ? hi : mi;
    PB2[t] = f ? hi : lo;
}

// ---------------------------------------------------------------------------
// k2: LDS-staged MFMA sim scan + top-8. Grid 512: block = 64-row group
// (blockIdx>>2; wave wv owns 16-row strip) x col quarter (blockIdx&3).
// Per chunk: stage 256 cols of PB1+PB2 (32 KB) into LDS with XOR swizzle
// q' = (q + ((c>>1)&3)) & 3  -> uniform 2-way banks (free, m136); consumer
// reads are 2 ds_read_b128/tile at a lane-constant swizzle offset. 3-limb
// MFMA chain; max-of-4 gate + cross-quad watermark (2 shfl/chunk) keep the
// insert body rare. C layout: col=lane&15 (i-row), row=q*4+reg (j).
// ---------------------------------------------------------------------------
__global__ __launch_bounds__(256, 4) void k2_topk(const ushort* __restrict__ PA1,
                                                  const ushort* __restrict__ PA2,
                                                  const ushort* __restrict__ PA3,
                                                  const ushort* __restrict__ PB1,
                                                  const ushort* __restrict__ PB2,
                                                  uint64_t* __restrict__ pp)
{
    __shared__ s8v lds[2048];   // 32 KB: [0..1023] PB1-chunk, [1024..2047] PB2-chunk

    const int tid   = threadIdx.x;
    const int lane  = tid & 63;
    const int wv    = tid >> 6;
    const int qtr   = blockIdx.x & 3;
    const int row0  = (blockIdx.x >> 2) * 64 + wv * 16;
    const int qcol0 = qtr * QWID;
    const int n     = lane & 15;   // i-row within strip
    const int q     = lane >> 4;   // k-quad / j-subgroup
    const int qs    = (q + ((n >> 1) & 3)) & 3;   // lane-constant read swizzle

    // stationary i-frags (B operand): row = row0 + n, k-slots q*8..q*8+7
    const size_t ioff = ((size_t)(row0 + n) << 5) + (q << 3);
    const s8v i1 = *(const s8v*)(PA1 + ioff);
    const s8v i2 = *(const s8v*)(PA2 + ioff);
    const s8v i3 = *(const s8v*)(PA3 + ioff);

    float    kv[8];
    uint32_t ki[8];
#pragma unroll
    for (int t = 0; t < 8; ++t) { kv[t] = -INFINITY; ki[t] = 0u; }
    float thr = -INFINITY;   // cross-quad watermark (refreshed per chunk)

    for (int cc = 0; cc < NCH; ++cc) {
        __syncthreads();
        // stage chunk: 2048 x 16B, swizzled; it<4 -> PB1, else PB2 (uniform)
#pragma unroll
        for (int it = 0; it < 8; ++it) {
            const int o  = it * 256 + tid;
            const int oo = o & 1023;
            const int c  = oo >> 2;
            const int qq = oo & 3;
            const int sw = (qq + ((c >> 1) & 3)) & 3;
            const ushort* src = (it < 4) ? PB1 : PB2;
            const int gcol = qcol0 + cc * CCOL + c;
            const s8v v = *(const s8v*)(src + ((size_t)gcol << 5) + (qq << 3));
            lds[((it < 4) ? 0 : 1024) + (c << 2) + sw] = v;
        }
        __syncthreads();

        // refresh cross-quad watermark: max over the 4 lanes holding this row
        {
            float t = kv[7];
            t = fmaxf(t, __shfl_xor(t, 16, 64));
            t = fmaxf(t, __shfl_xor(t, 32, 64));
            thr = t;
        }

        const int base = (n << 2) + qs;
#pragma unroll 4
        for (int t = 0; t < TPC; ++t) {
            const s8v jb1 = lds[t * 64 + base];
            const s8v jb2 = lds[1024 + t * 64 + base];

            f4v acc = {0.f, 0.f, 0.f, 0.f};
            acc = __builtin_amdgcn_mfma_f32_16x16x32_bf16(jb1, i1, acc, 0, 0, 0);
            acc = __builtin_amdgcn_mfma_f32_16x16x32_bf16(jb2, i2, acc, 0, 0, 0);
            acc = __builtin_amdgcn_mfma_f32_16x16x32_bf16(jb1, i3, acc, 0, 0, 0);

            const float vm = fmaxf(fmaxf(acc[0], acc[1]), fmaxf(acc[2], acc[3]));
            if (__builtin_expect(vm > kv[7] && vm >= thr, 0)) {
                const uint32_t jbase = (uint32_t)(qcol0 + cc * CCOL + t * 16 + (q << 2));
#pragma unroll
                for (int g = 0; g < 4; ++g) {
                    const float v = acc[g];
                    if (v > kv[7] && v >= thr) {
                        kv[7] = v; ki[7] = jbase + g;
#pragma unroll
                        for (int s = 7; s >= 1; --s) {      // bubble up, strict >
                            const bool sw2 = kv[s] > kv[s - 1];
                            const float    av = sw2 ? kv[s]     : kv[s - 1];
                            const float    bv = sw2 ? kv[s - 1] : kv[s];
                            const uint32_t ai = sw2 ? ki[s]     : ki[s - 1];
                            const uint32_t bi = sw2 ? ki[s - 1] : ki[s];
                            kv[s - 1] = av; kv[s] = bv;
                            ki[s - 1] = ai; ki[s] = bi;
                        }
                    }
                }
            }
        }
    }

    // pack u64 keys; butterfly-merge across the 4 quad-lanes of this i-row
    uint64_t lst[8];
#pragma unroll
    for (int t = 0; t < 8; ++t)
        lst[t] = ((uint64_t)fflip(kv[t]) << 32) | (uint64_t)(~ki[t]);

#pragma unroll
    for (int mm = 16; mm <= 32; mm <<= 1) {
        uint64_t o[8];
#pragma unroll
        for (int t = 0; t < 8; ++t)
            o[t] = (uint64_t)__shfl_xor((unsigned long long)lst[t], mm, 64);
        uint64_t X[8];
#pragma unroll
        for (int t = 0; t < 8; ++t) X[t] = kmax(lst[t], o[7 - t]);
#define CSWP(i, jx) { const uint64_t hi = kmax(X[i], X[jx]); const uint64_t lo = kmin(X[i], X[jx]); X[i] = hi; X[jx] = lo; }
        CSWP(0,4) CSWP(1,5) CSWP(2,6) CSWP(3,7)
        CSWP(0,2) CSWP(1,3) CSWP(4,6) CSWP(5,7)
        CSWP(0,1) CSWP(2,3) CSWP(4,5) CSWP(6,7)
#undef CSWP
#pragma unroll
        for (int t = 0; t < 8; ++t) lst[t] = X[t];
    }

    if (q == 0) {
        const int row = row0 + n;
        uint64_t* dst = pp + ((size_t)qtr * NN + row) * 8;
#pragma unroll
        for (int t = 0; t < 8; ++t) dst[t] = lst[t];
    }
}

// ---------------------------------------------------------------------------
// k2m: 4-way merge of per-quarter sorted lists; emit neighbor idx/val
// (rank 0 = self, dropped). One thread per row; heads cached in registers.
// ---------------------------------------------------------------------------
__global__ __launch_bounds__(256) void k2_merge(const uint64_t* __restrict__ pp,
                                                int* __restrict__ nbr_idx,
                                                float* __restrict__ nbr_val)
{
    const int row = blockIdx.x * 256 + threadIdx.x;
    uint64_t hd[SN]; int ix[SN];
#pragma unroll
    for (int s = 0; s < SN; ++s) { hd[s] = pp[((size_t)s * NN + row) * 8]; ix[s] = 0; }
#pragma unroll
    for (int t = 0; t < 7; ++t) {
        uint64_t best = hd[0]; int bs = 0;
#pragma unroll
        for (int s = 1; s < SN; ++s)
            if (hd[s] > best) { best = hd[s]; bs = s; }
        ++ix[bs];
        hd[bs] = pp[((size_t)bs * NN + row) * 8 + ix[bs]];   // ix <= 7, in-bounds
        if (t >= 1) {
            uint32_t u = (uint32_t)(best >> 32);
            u = (u & 0x80000000u) ? (u & 0x7fffffffu) : ~u;
            nbr_val[(size_t)row * KN + (t - 1)] = __uint_as_float(u);
            nbr_idx[(size_t)row * KN + (t - 1)] = (int)~(uint32_t)best;
        }
    }
}

// ---------------------------------------------------------------------------
// k3: zero-fill d_out — grid-stride, plain coherent float4 stores
// ---------------------------------------------------------------------------
__global__ __launch_bounds__(256) void k3_zero(float4* __restrict__ out)
{
    const size_t base = (size_t)blockIdx.x * 1024 + threadIdx.x;
    const float4 z = make_float4(0.f, 0.f, 0.f, 0.f);
#pragma unroll
    for (int qq = 0; qq < 4; ++qq)
        out[base + (size_t)qq * 256] = z;
}

// ---------------------------------------------------------------------------
// k4: rs[i] = row sums of symmetrized sparse matrix
// ---------------------------------------------------------------------------
__global__ __launch_bounds__(256) void k4_rowsum(const int* __restrict__ nbr_idx,
                                                 const float* __restrict__ nbr_val,
                                                 float* __restrict__ rs)
{
    const int e = blockIdx.x * 256 + threadIdx.x;
    const int i = e / KN;
    const int j = nbr_idx[e];
    const float v = nbr_val[e] * 0.5f;
    atomicAdd(&rs[i], v);
    atomicAdd(&rs[j], v);
}

// ---------------------------------------------------------------------------
// k5: scatter normalized values into pre-zeroed dense output
// ---------------------------------------------------------------------------
__global__ __launch_bounds__(256) void k5_scatter(const int* __restrict__ nbr_idx,
                                                  const float* __restrict__ nbr_val,
                                                  const float* __restrict__ rs,
                                                  float* __restrict__ out)
{
    const int e = blockIdx.x * 256 + threadIdx.x;
    const int i = e / KN;
    const int j = nbr_idx[e];
    const float v = nbr_val[e] * 0.5f;
    const float wi = v / (rs[i] + 1e-8f);
    const float wj = v / (rs[j] + 1e-8f);
    atomicAdd(out + (size_t)i * NN + j, wi);
    atomicAdd(out + (size_t)j * NN + i, wj);
}

// ---------------------------------------------------------------------------
extern "C" void kernel_launch(void* const* d_in, const int* in_sizes, int n_in,
                              void* d_out, int out_size, void* d_ws, size_t ws_size,
                              hipStream_t stream)
{
    const float* x = (const float*)d_in[0];   // 8192 x 256
    const float* W = (const float*)d_in[1];   // 16 x 256
    const float* b = (const float*)d_in[2];   // 16
    float* out = (float*)d_out;               // 8192 x 8192

    // workspace layout (~7 MB); pp first for 8B alignment
    uint64_t* pp = (uint64_t*)d_ws;                  // SN*NN*8 keys (2 MB)
    float* h  = (float*)(pp + (size_t)SN * NN * 8);  // NN*HID
    float* rs = h + (size_t)NN * HID;                // NN
    float* nv = rs + NN;                             // NN*KN
    int*   ni = (int*)(nv + (size_t)NN * KN);        // NN*KN
    ushort* PA1 = (ushort*)(ni + (size_t)NN * KN);   // NN*32 each, 16B-aligned
    ushort* PA2 = PA1 + (size_t)NN * 32;
    ushort* PA3 = PA2 + (size_t)NN * 32;
    ushort* PB1 = PA3 + (size_t)NN * 32;
    ushort* PB2 = PB1 + (size_t)NN * 32;

    k1_embed <<<NN / 4,            256, 0, stream>>>(x, W, b, h, rs);
    k1b_split<<<(NN * 32) / 256,   256, 0, stream>>>(h, PA1, PA2, PA3, PB1, PB2);
    k2_topk  <<<(NN / 64) * SN,    256, 0, stream>>>(PA1, PA2, PA3, PB1, PB2, pp);
    k2_merge <<<NN / 256,          256, 0, stream>>>(pp, ni, nv);
    k3_zero  <<<(int)(((size_t)NN * NN / 4) / 1024), 256, 0, stream>>>((float4*)out);
    k4_rowsum<<<(NN * KN) / 256,   256, 0, stream>>>(ni, nv, rs);
    k5_scatter<<<(NN * KN) / 256,  256, 0, stream>>>(ni, nv, rs, out);
}

// Round 12
// 388.775 us; speedup vs baseline: 1.6470x; 1.6470x over previous
//
#include <hip/hip_runtime.h>
#include <stdint.h>
#include <math.h>

#define NN   8192
#define IND  256
#define HID  16
#define KN   6
#define SEG  8          // col segments
#define SW   (NN/SEG)   // 1024 cols per segment
#define CCOL 256        // cols per LDS chunk
#define NCH  (SW/CCOL)  // 4 chunks per block
#define TPC  (CCOL/16)  // 16 tiles per chunk

typedef short s8v  __attribute__((ext_vector_type(8)));
typedef float f4v  __attribute__((ext_vector_type(4)));

__device__ __forceinline__ uint64_t kmax(uint64_t a, uint64_t b) { return a > b ? a : b; }

__device__ __forceinline__ uint32_t fflip(float f) {
    const uint32_t u = __float_as_uint(f);
    return (u & 0x80000000u) ? ~u : (u | 0x80000000u);
}

__device__ __forceinline__ uint32_t bf16_rne_bits(float x) {
    const uint32_t u = __float_as_uint(x);
    return (u + 0x7FFFu + ((u >> 16) & 1u)) & 0xFFFF0000u;
}

// ---------------------------------------------------------------------------
// k1: h[i] = normalize(x[i] @ W^T + b), also zero rs[i].
// ---------------------------------------------------------------------------
__global__ __launch_bounds__(256) void k1_embed(const float* __restrict__ x,
                                                const float* __restrict__ W,
                                                const float* __restrict__ b,
                                                float* __restrict__ h,
                                                float* __restrict__ rs)
{
    const int lane = threadIdx.x & 63;
    const int wv   = threadIdx.x >> 6;
    const int row  = blockIdx.x * 4 + wv;

    const float4 xv = *(const float4*)(x + (size_t)row * IND + lane * 4);

    float acc[HID];
#pragma unroll
    for (int k = 0; k < HID; ++k) {
        const float4 wv4 = *(const float4*)(W + (size_t)k * IND + lane * 4);
        float v = xv.x * wv4.x + xv.y * wv4.y + xv.z * wv4.z + xv.w * wv4.w;
#pragma unroll
        for (int m = 32; m >= 1; m >>= 1) v += __shfl_xor(v, m, 64);
        acc[k] = v;
    }

    if (lane == 0) {
        float hv[HID];
        float ss = 0.f;
#pragma unroll
        for (int k = 0; k < HID; ++k) { hv[k] = acc[k] + b[k]; ss += hv[k] * hv[k]; }
        const float nrm = fmaxf(sqrtf(ss), 1e-12f);
#pragma unroll
        for (int k = 0; k < HID; ++k) hv[k] = hv[k] / nrm;
        float4* hp = (float4*)(h + (size_t)row * HID);
        hp[0] = make_float4(hv[0],  hv[1],  hv[2],  hv[3]);
        hp[1] = make_float4(hv[4],  hv[5],  hv[6],  hv[7]);
        hp[2] = make_float4(hv[8],  hv[9],  hv[10], hv[11]);
        hp[3] = make_float4(hv[12], hv[13], hv[14], hv[15]);
        rs[row] = 0.f;
    }
}

// ---------------------------------------------------------------------------
// k1b: 3 exact bf16 limbs; 5 K=32 packings (verified R8-R11):
// PA1=[hi|hi] PA2=[mid|hi] PA3=[lo|mid] (i side), PB1=[hi|mid] PB2=[hi|lo]
// (j side). mfma(PB1,PA1)+mfma(PB2,PA2)+mfma(PB1,PA3) -> ~6e-8 per-sim err.
// ---------------------------------------------------------------------------
__global__ __launch_bounds__(256) void k1b_split(const float* __restrict__ h,
                                                 ushort* __restrict__ PA1,
                                                 ushort* __restrict__ PA2,
                                                 ushort* __restrict__ PA3,
                                                 ushort* __restrict__ PB1,
                                                 ushort* __restrict__ PB2)
{
    const int t   = blockIdx.x * 256 + threadIdx.x;   // < NN*32
    const int row = t >> 5;
    const int s   = t & 31;
    const int k   = s & 15;

    const float x = h[(size_t)row * HID + k];
    const uint32_t hb = bf16_rne_bits(x);
    const float r1 = x - __uint_as_float(hb);
    const uint32_t mb = bf16_rne_bits(r1);
    const float r2 = r1 - __uint_as_float(mb);
    const uint32_t lb = bf16_rne_bits(r2);
    const ushort hi = (ushort)(hb >> 16);
    const ushort mi = (ushort)(mb >> 16);
    const ushort lo = (ushort)(lb >> 16);

    const bool f = (s < 16);
    PA1[t] = hi;
    PA2[t] = f ? mi : hi;
    PA3[t] = f ? lo : mi;
    PB1[t] = f ? hi : mi;
    PB2[t] = f ? hi : lo;
}

// sorted-desc 8-list utilities (branch-free)
#define CSWPF(X,i,j) { const float _h = fmaxf(X[i], X[j]); const float _l = fminf(X[i], X[j]); X[i] = _h; X[j] = _l; }
#define BSTAGES(X) CSWPF(X,0,4) CSWPF(X,1,5) CSWPF(X,2,6) CSWPF(X,3,7) \
                   CSWPF(X,0,2) CSWPF(X,1,3) CSWPF(X,4,6) CSWPF(X,5,7) \
                   CSWPF(X,0,1) CSWPF(X,2,3) CSWPF(X,4,5) CSWPF(X,6,7)

// ---------------------------------------------------------------------------
// p1: branch-free value scan. Block = 64 rows x segment (grid 1024). Per
// tile: 2 swizzled ds_read_b128 + 3-limb MFMA + 4 independent 16-op
// insertion networks (fmax/fmin only — NO branches, NO exec masking; this
// was the R1-R11 structural cost). Epilogue: 3 bitonic merges + 2-step shfl
// quad merge -> per-(segment,row) sorted top-8 values.
// ---------------------------------------------------------------------------
__global__ __launch_bounds__(256, 4) void p1_scan(const ushort* __restrict__ PA1,
                                                  const ushort* __restrict__ PA2,
                                                  const ushort* __restrict__ PA3,
                                                  const ushort* __restrict__ PB1,
                                                  const ushort* __restrict__ PB2,
                                                  float* __restrict__ tq)
{
    __shared__ s8v lds[2048];   // 32 KB: PB1 chunk | PB2 chunk

    const int tid  = threadIdx.x;
    const int lane = tid & 63;
    const int wv   = tid >> 6;
    const int seg  = blockIdx.x & (SEG - 1);
    const int row0 = (blockIdx.x >> 3) * 64 + wv * 16;
    const int n    = lane & 15;
    const int q    = lane >> 4;
    const int qs   = (q + ((n >> 1) & 3)) & 3;

    const size_t ioff = ((size_t)(row0 + n) << 5) + (q << 3);
    const s8v i1 = *(const s8v*)(PA1 + ioff);
    const s8v i2 = *(const s8v*)(PA2 + ioff);
    const s8v i3 = *(const s8v*)(PA3 + ioff);

    float La[8], Lb[8], Lc[8], Ld[8];
#pragma unroll
    for (int t = 0; t < 8; ++t) { La[t] = -INFINITY; Lb[t] = -INFINITY; Lc[t] = -INFINITY; Ld[t] = -INFINITY; }

    for (int cc = 0; cc < NCH; ++cc) {
        __syncthreads();
#pragma unroll
        for (int it = 0; it < 8; ++it) {
            const int o  = it * 256 + tid;
            const int oo = o & 1023;
            const int c  = oo >> 2;
            const int qq = oo & 3;
            const int sw = (qq + ((c >> 1) & 3)) & 3;
            const ushort* src = (it < 4) ? PB1 : PB2;
            const int gcol = seg * SW + cc * CCOL + c;
            const s8v v = *(const s8v*)(src + ((size_t)gcol << 5) + (qq << 3));
            lds[((it < 4) ? 0 : 1024) + (c << 2) + sw] = v;
        }
        __syncthreads();

        const int base = (n << 2) + qs;
#pragma unroll 4
        for (int t = 0; t < TPC; ++t) {
            const s8v jb1 = lds[t * 64 + base];
            const s8v jb2 = lds[1024 + t * 64 + base];

            f4v acc = {0.f, 0.f, 0.f, 0.f};
            acc = __builtin_amdgcn_mfma_f32_16x16x32_bf16(jb1, i1, acc, 0, 0, 0);
            acc = __builtin_amdgcn_mfma_f32_16x16x32_bf16(jb2, i2, acc, 0, 0, 0);
            acc = __builtin_amdgcn_mfma_f32_16x16x32_bf16(jb1, i3, acc, 0, 0, 0);

            float v0 = acc[0], v1 = acc[1], v2 = acc[2], v3 = acc[3];
#pragma unroll
            for (int s = 0; s < 8; ++s) {   // 4 parallel branchless insertions
                const float h0 = fmaxf(La[s], v0); v0 = fminf(La[s], v0); La[s] = h0;
                const float h1 = fmaxf(Lb[s], v1); v1 = fminf(Lb[s], v1); Lb[s] = h1;
                const float h2 = fmaxf(Lc[s], v2); v2 = fminf(Lc[s], v2); Lc[s] = h2;
                const float h3 = fmaxf(Ld[s], v3); v3 = fminf(Ld[s], v3); Ld[s] = h3;
            }
        }
    }

    // merge the 4 lists (bitonic, branch-free)
    float M1[8], M2[8], R[8];
#pragma unroll
    for (int t = 0; t < 8; ++t) M1[t] = fmaxf(La[t], Lb[7 - t]);
    BSTAGES(M1)
#pragma unroll
    for (int t = 0; t < 8; ++t) M2[t] = fmaxf(Lc[t], Ld[7 - t]);
    BSTAGES(M2)
#pragma unroll
    for (int t = 0; t < 8; ++t) R[t] = fmaxf(M1[t], M2[7 - t]);
    BSTAGES(R)

    // quad merge across the 4 lanes of this row
#pragma unroll
    for (int mm = 16; mm <= 32; mm <<= 1) {
        float o[8], X[8];
#pragma unroll
        for (int t = 0; t < 8; ++t) o[t] = __shfl_xor(R[t], mm, 64);
#pragma unroll
        for (int t = 0; t < 8; ++t) X[t] = fmaxf(R[t], o[7 - t]);
        BSTAGES(X)
#pragma unroll
        for (int t = 0; t < 8; ++t) R[t] = X[t];
    }

    if (q == 0) {
        float* dst = tq + ((size_t)seg * NN + (row0 + n)) * 8;
#pragma unroll
        for (int t = 0; t < 8; ++t) dst[t] = R[t];
    }
}

// ---------------------------------------------------------------------------
// p15: tau[row] = 8th-largest value over the 8 per-segment sorted lists;
// zero cnt[row]. One thread per row.
// ---------------------------------------------------------------------------
__global__ __launch_bounds__(256) void p15_tau(const float* __restrict__ tq,
                                               float* __restrict__ tau,
                                               int* __restrict__ cnt)
{
    const int row = blockIdx.x * 256 + threadIdx.x;
    float hd[SEG]; int ix[SEG];
#pragma unroll
    for (int s = 0; s < SEG; ++s) { hd[s] = tq[((size_t)s * NN + row) * 8]; ix[s] = 0; }
    float tv = -INFINITY;
#pragma unroll
    for (int t = 0; t < 8; ++t) {
        float best = hd[0]; int bs = 0;
#pragma unroll
        for (int s = 1; s < SEG; ++s)
            if (hd[s] > best) { best = hd[s]; bs = s; }
        tv = best;
        ++ix[bs];
        hd[bs] = (ix[bs] < 8) ? tq[((size_t)bs * NN + row) * 8 + ix[bs]] : -INFINITY;
    }
    tau[row] = tv;
    cnt[row] = 0;
}

// ---------------------------------------------------------------------------
// p2: re-scan (bitwise-identical MFMA values) and append candidates with
// v >= tau[row] (count >= 8 incl. self, <= 16 barring 9-way float ties).
// Gate opens ~25% of tiles; body is tiny (atomicAdd + 2 stores).
// ---------------------------------------------------------------------------
__global__ __launch_bounds__(256, 4) void p2_emit(const ushort* __restrict__ PA1,
                                                  const ushort* __restrict__ PA2,
                                                  const ushort* __restrict__ PA3,
                                                  const ushort* __restrict__ PB1,
                                                  const ushort* __restrict__ PB2,
                                                  const float* __restrict__ tau,
                                                  int* __restrict__ cnt,
                                                  float* __restrict__ candv,
                                                  int* __restrict__ candj)
{
    __shared__ s8v lds[2048];

    const int tid  = threadIdx.x;
    const int lane = tid & 63;
    const int wv   = tid >> 6;
    const int seg  = blockIdx.x & (SEG - 1);
    const int row0 = (blockIdx.x >> 3) * 64 + wv * 16;
    const int n    = lane & 15;
    const int q    = lane >> 4;
    const int qs   = (q + ((n >> 1) & 3)) & 3;
    const int row  = row0 + n;

    const size_t ioff = ((size_t)row << 5) + (q << 3);
    const s8v i1 = *(const s8v*)(PA1 + ioff);
    const s8v i2 = *(const s8v*)(PA2 + ioff);
    const s8v i3 = *(const s8v*)(PA3 + ioff);
    const float tv = tau[row];

    for (int cc = 0; cc < NCH; ++cc) {
        __syncthreads();
#pragma unroll
        for (int it = 0; it < 8; ++it) {
            const int o  = it * 256 + tid;
            const int oo = o & 1023;
            const int c  = oo >> 2;
            const int qq = oo & 3;
            const int sw = (qq + ((c >> 1) & 3)) & 3;
            const ushort* src = (it < 4) ? PB1 : PB2;
            const int gcol = seg * SW + cc * CCOL + c;
            const s8v v = *(const s8v*)(src + ((size_t)gcol << 5) + (qq << 3));
            lds[((it < 4) ? 0 : 1024) + (c << 2) + sw] = v;
        }
        __syncthreads();

        const int base = (n << 2) + qs;
#pragma unroll 4
        for (int t = 0; t < TPC; ++t) {
            const s8v jb1 = lds[t * 64 + base];
            const s8v jb2 = lds[1024 + t * 64 + base];

            f4v acc = {0.f, 0.f, 0.f, 0.f};
            acc = __builtin_amdgcn_mfma_f32_16x16x32_bf16(jb1, i1, acc, 0, 0, 0);
            acc = __builtin_amdgcn_mfma_f32_16x16x32_bf16(jb2, i2, acc, 0, 0, 0);
            acc = __builtin_amdgcn_mfma_f32_16x16x32_bf16(jb1, i3, acc, 0, 0, 0);

            const float vm = fmaxf(fmaxf(acc[0], acc[1]), fmaxf(acc[2], acc[3]));
            if (__builtin_expect(vm >= tv, 0)) {
                const int jbase = seg * SW + cc * CCOL + t * 16 + (q << 2);
#pragma unroll
                for (int g = 0; g < 4; ++g) {
                    if (acc[g] >= tv) {
                        const int idx = atomicAdd(&cnt[row], 1);
                        if (idx < 16) {
                            candv[(size_t)row * 16 + idx] = acc[g];
                            candj[(size_t)row * 16 + idx] = jbase + g;
                        }
                    }
                }
            }
        }
    }
}

// ---------------------------------------------------------------------------
// p3: exact top-7 over <=16 candidates per row, (value desc, index asc);
// rank 0 = self, dropped; emit neighbor idx/val. One thread per row.
// ---------------------------------------------------------------------------
__global__ __launch_bounds__(256) void p3_select(const int* __restrict__ cnt,
                                                 const float* __restrict__ candv,
                                                 const int* __restrict__ candj,
                                                 int* __restrict__ nbr_idx,
                                                 float* __restrict__ nbr_val)
{
    const int row = blockIdx.x * 256 + threadIdx.x;
    const int c = min(cnt[row], 16);
    uint64_t keys[16];
    for (int i = 0; i < c; ++i) {
        const float v = candv[(size_t)row * 16 + i];
        const uint32_t j = (uint32_t)candj[(size_t)row * 16 + i];
        keys[i] = ((uint64_t)fflip(v) << 32) | (uint64_t)(~j);
    }
    for (int t = 0; t < 7; ++t) {
        uint64_t best = 0; int bi = 0;
        for (int i = 0; i < c; ++i)
            if (keys[i] > best) { best = keys[i]; bi = i; }
        keys[bi] = 0;
        if (t >= 1) {
            uint32_t u = (uint32_t)(best >> 32);
            u = (u & 0x80000000u) ? (u & 0x7fffffffu) : ~u;
            nbr_val[(size_t)row * KN + (t - 1)] = __uint_as_float(u);
            nbr_idx[(size_t)row * KN + (t - 1)] = (int)~(uint32_t)best;
        }
    }
}

// ---------------------------------------------------------------------------
// k3: zero-fill d_out — grid-stride, plain coherent float4 stores
// ---------------------------------------------------------------------------
__global__ __launch_bounds__(256) void k3_zero(float4* __restrict__ out)
{
    const size_t base = (size_t)blockIdx.x * 1024 + threadIdx.x;
    const float4 z = make_float4(0.f, 0.f, 0.f, 0.f);
#pragma unroll
    for (int qq = 0; qq < 4; ++qq)
        out[base + (size_t)qq * 256] = z;
}

// ---------------------------------------------------------------------------
// k4: rs[i] = row sums of symmetrized sparse matrix
// ---------------------------------------------------------------------------
__global__ __launch_bounds__(256) void k4_rowsum(const int* __restrict__ nbr_idx,
                                                 const float* __restrict__ nbr_val,
                                                 float* __restrict__ rs)
{
    const int e = blockIdx.x * 256 + threadIdx.x;
    const int i = e / KN;
    const int j = nbr_idx[e];
    const float v = nbr_val[e] * 0.5f;
    atomicAdd(&rs[i], v);
    atomicAdd(&rs[j], v);
}

// ---------------------------------------------------------------------------
// k5: scatter normalized values into pre-zeroed dense output
// ---------------------------------------------------------------------------
__global__ __launch_bounds__(256) void k5_scatter(const int* __restrict__ nbr_idx,
                                                  const float* __restrict__ nbr_val,
                                                  const float* __restrict__ rs,
                                                  float* __restrict__ out)
{
    const int e = blockIdx.x * 256 + threadIdx.x;
    const int i = e / KN;
    const int j = nbr_idx[e];
    const float v = nbr_val[e] * 0.5f;
    const float wi = v / (rs[i] + 1e-8f);
    const float wj = v / (rs[j] + 1e-8f);
    atomicAdd(out + (size_t)i * NN + j, wi);
    atomicAdd(out + (size_t)j * NN + i, wj);
}

// ---------------------------------------------------------------------------
extern "C" void kernel_launch(void* const* d_in, const int* in_sizes, int n_in,
                              void* d_out, int out_size, void* d_ws, size_t ws_size,
                              hipStream_t stream)
{
    const float* x = (const float*)d_in[0];   // 8192 x 256
    const float* W = (const float*)d_in[1];   // 16 x 256
    const float* b = (const float*)d_in[2];   // 16
    float* out = (float*)d_out;               // 8192 x 8192

    // workspace layout (~6 MB), all boundaries multiples of NN elements
    float* tq    = (float*)d_ws;                      // SEG*NN*8
    float* tau   = tq + (size_t)SEG * NN * 8;         // NN
    float* h     = tau + NN;                          // NN*HID
    float* rs    = h + (size_t)NN * HID;              // NN
    float* nv    = rs + NN;                           // NN*KN
    float* candv = nv + (size_t)NN * KN;              // NN*16
    int*   ni    = (int*)(candv + (size_t)NN * 16);   // NN*KN
    int*   candj = ni + (size_t)NN * KN;              // NN*16
    int*   cnt   = candj + (size_t)NN * 16;           // NN
    ushort* PA1  = (ushort*)(cnt + NN);               // NN*32 each
    ushort* PA2  = PA1 + (size_t)NN * 32;
    ushort* PA3  = PA2 + (size_t)NN * 32;
    ushort* PB1  = PA3 + (size_t)NN * 32;
    ushort* PB2  = PB1 + (size_t)NN * 32;

    k1_embed <<<NN / 4,            256, 0, stream>>>(x, W, b, h, rs);
    k1b_split<<<(NN * 32) / 256,   256, 0, stream>>>(h, PA1, PA2, PA3, PB1, PB2);
    p1_scan  <<<(NN / 64) * SEG,   256, 0, stream>>>(PA1, PA2, PA3, PB1, PB2, tq);
    p15_tau  <<<NN / 256,          256, 0, stream>>>(tq, tau, cnt);
    p2_emit  <<<(NN / 64) * SEG,   256, 0, stream>>>(PA1, PA2, PA3, PB1, PB2, tau, cnt, candv, candj);
    p3_select<<<NN / 256,          256, 0, stream>>>(cnt, candv, candj, ni, nv);
    k3_zero  <<<(int)(((size_t)NN * NN / 4) / 1024), 256, 0, stream>>>((float4*)out);
    k4_rowsum<<<(NN * KN) / 256,   256, 0, stream>>>(ni, nv, rs);
    k5_scatter<<<(NN * KN) / 256,  256, 0, stream>>>(ni, nv, rs, out);
}

// Round 13
// 367.322 us; speedup vs baseline: 1.7432x; 1.0584x over previous
//
#include <hip/hip_runtime.h>
#include <stdint.h>
#include <math.h>

#define NN   8192
#define IND  256
#define HID  16
#define KN   6
#define SEG  8          // col segments
#define SW   (NN/SEG)   // 1024 cols per segment
#define CCOL 256        // cols per LDS chunk
#define NCH  (SW/CCOL)  // 4 chunks per block
#define TPC  (CCOL/16)  // 16 tiles per chunk

typedef short s8v  __attribute__((ext_vector_type(8)));
typedef float f4v  __attribute__((ext_vector_type(4)));

__device__ __forceinline__ uint32_t fflip(float f) {
    const uint32_t u = __float_as_uint(f);
    return (u & 0x80000000u) ? ~u : (u | 0x80000000u);
}

__device__ __forceinline__ uint32_t bf16_rne_bits(float x) {
    const uint32_t u = __float_as_uint(x);
    return (u + 0x7FFFu + ((u >> 16) & 1u)) & 0xFFFF0000u;
}

// ---------------------------------------------------------------------------
// k1: h[i] = normalize(x[i] @ W^T + b), also zero rs[i].
// ---------------------------------------------------------------------------
__global__ __launch_bounds__(256) void k1_embed(const float* __restrict__ x,
                                                const float* __restrict__ W,
                                                const float* __restrict__ b,
                                                float* __restrict__ h,
                                                float* __restrict__ rs)
{
    const int lane = threadIdx.x & 63;
    const int wv   = threadIdx.x >> 6;
    const int row  = blockIdx.x * 4 + wv;

    const float4 xv = *(const float4*)(x + (size_t)row * IND + lane * 4);

    float acc[HID];
#pragma unroll
    for (int k = 0; k < HID; ++k) {
        const float4 wv4 = *(const float4*)(W + (size_t)k * IND + lane * 4);
        float v = xv.x * wv4.x + xv.y * wv4.y + xv.z * wv4.z + xv.w * wv4.w;
#pragma unroll
        for (int m = 32; m >= 1; m >>= 1) v += __shfl_xor(v, m, 64);
        acc[k] = v;
    }

    if (lane == 0) {
        float hv[HID];
        float ss = 0.f;
#pragma unroll
        for (int k = 0; k < HID; ++k) { hv[k] = acc[k] + b[k]; ss += hv[k] * hv[k]; }
        const float nrm = fmaxf(sqrtf(ss), 1e-12f);
#pragma unroll
        for (int k = 0; k < HID; ++k) hv[k] = hv[k] / nrm;
        float4* hp = (float4*)(h + (size_t)row * HID);
        hp[0] = make_float4(hv[0],  hv[1],  hv[2],  hv[3]);
        hp[1] = make_float4(hv[4],  hv[5],  hv[6],  hv[7]);
        hp[2] = make_float4(hv[8],  hv[9],  hv[10], hv[11]);
        hp[3] = make_float4(hv[12], hv[13], hv[14], hv[15]);
        rs[row] = 0.f;
    }
}

// ---------------------------------------------------------------------------
// k1b: 3 exact bf16 limbs; 5 K=32 packings (verified R8-R12):
// PA1=[hi|hi] PA2=[mid|hi] PA3=[lo|mid] (i side), PB1=[hi|mid] PB2=[hi|lo]
// (j side). mfma(PB1,PA1)+mfma(PB2,PA2)+mfma(PB1,PA3) -> ~6e-8 per-sim err.
// ---------------------------------------------------------------------------
__global__ __launch_bounds__(256) void k1b_split(const float* __restrict__ h,
                                                 ushort* __restrict__ PA1,
                                                 ushort* __restrict__ PA2,
                                                 ushort* __restrict__ PA3,
                                                 ushort* __restrict__ PB1,
                                                 ushort* __restrict__ PB2)
{
    const int t   = blockIdx.x * 256 + threadIdx.x;   // < NN*32
    const int row = t >> 5;
    const int s   = t & 31;
    const int k   = s & 15;

    const float x = h[(size_t)row * HID + k];
    const uint32_t hb = bf16_rne_bits(x);
    const float r1 = x - __uint_as_float(hb);
    const uint32_t mb = bf16_rne_bits(r1);
    const float r2 = r1 - __uint_as_float(mb);
    const uint32_t lb = bf16_rne_bits(r2);
    const ushort hi = (ushort)(hb >> 16);
    const ushort mi = (ushort)(mb >> 16);
    const ushort lo = (ushort)(lb >> 16);

    const bool f = (s < 16);
    PA1[t] = hi;
    PA2[t] = f ? mi : hi;
    PA3[t] = f ? lo : mi;
    PB1[t] = f ? hi : mi;
    PB2[t] = f ? hi : lo;
}

// branch-free comparators (desc)
#define CSWPF(X,i,j) { const float _h = fmaxf(X[i], X[j]); const float _l = fminf(X[i], X[j]); X[i] = _h; X[j] = _l; }
#define CSWPV(a,b)   { const float _h = fmaxf(a, b); const float _l = fminf(a, b); a = _h; b = _l; }
#define BSTAGES(X) CSWPF(X,0,4) CSWPF(X,1,5) CSWPF(X,2,6) CSWPF(X,3,7) \
                   CSWPF(X,0,2) CSWPF(X,1,3) CSWPF(X,4,6) CSWPF(X,5,7) \
                   CSWPF(X,0,1) CSWPF(X,2,3) CSWPF(X,4,5) CSWPF(X,6,7)

// ---------------------------------------------------------------------------
// p1: branch-free value scan. Block = 64 rows x segment (grid 1024). Per
// tile: 2 swizzled ds_read_b128 + 3-limb MFMA + sort-4 (5 comparators) +
// bitonic top-8 merge (4 fmax + 12 comparators) into ONE per-lane list —
// all 4 C-values are the same row, so a single list is exact (R12 used 4
// lists = 64 VALU/tile; this is 38). Epilogue: 2-step shfl quad merge ->
// per-(segment,row) sorted top-8 values.
// ---------------------------------------------------------------------------
__global__ __launch_bounds__(256, 4) void p1_scan(const ushort* __restrict__ PA1,
                                                  const ushort* __restrict__ PA2,
                                                  const ushort* __restrict__ PA3,
                                                  const ushort* __restrict__ PB1,
                                                  const ushort* __restrict__ PB2,
                                                  float* __restrict__ tq)
{
    __shared__ s8v lds[2048];   // 32 KB: PB1 chunk | PB2 chunk

    const int tid  = threadIdx.x;
    const int lane = tid & 63;
    const int wv   = tid >> 6;
    const int seg  = blockIdx.x & (SEG - 1);
    const int row0 = (blockIdx.x >> 3) * 64 + wv * 16;
    const int n    = lane & 15;
    const int q    = lane >> 4;
    const int qs   = (q + ((n >> 1) & 3)) & 3;

    const size_t ioff = ((size_t)(row0 + n) << 5) + (q << 3);
    const s8v i1 = *(const s8v*)(PA1 + ioff);
    const s8v i2 = *(const s8v*)(PA2 + ioff);
    const s8v i3 = *(const s8v*)(PA3 + ioff);

    float L[8];
#pragma unroll
    for (int t = 0; t < 8; ++t) L[t] = -INFINITY;

    for (int cc = 0; cc < NCH; ++cc) {
        __syncthreads();
#pragma unroll
        for (int it = 0; it < 8; ++it) {
            const int o  = it * 256 + tid;
            const int oo = o & 1023;
            const int c  = oo >> 2;
            const int qq = oo & 3;
            const int sw = (qq + ((c >> 1) & 3)) & 3;
            const ushort* src = (it < 4) ? PB1 : PB2;
            const int gcol = seg * SW + cc * CCOL + c;
            const s8v v = *(const s8v*)(src + ((size_t)gcol << 5) + (qq << 3));
            lds[((it < 4) ? 0 : 1024) + (c << 2) + sw] = v;
        }
        __syncthreads();

        const int base = (n << 2) + qs;
#pragma unroll 4
        for (int t = 0; t < TPC; ++t) {
            const s8v jb1 = lds[t * 64 + base];
            const s8v jb2 = lds[1024 + t * 64 + base];

            f4v acc = {0.f, 0.f, 0.f, 0.f};
            acc = __builtin_amdgcn_mfma_f32_16x16x32_bf16(jb1, i1, acc, 0, 0, 0);
            acc = __builtin_amdgcn_mfma_f32_16x16x32_bf16(jb2, i2, acc, 0, 0, 0);
            acc = __builtin_amdgcn_mfma_f32_16x16x32_bf16(jb1, i3, acc, 0, 0, 0);

            // sort 4 values desc (5 comparators)
            float s0 = acc[0], s1 = acc[1], s2 = acc[2], s3 = acc[3];
            CSWPV(s0, s1) CSWPV(s2, s3) CSWPV(s0, s2) CSWPV(s1, s3) CSWPV(s1, s2)

            // bitonic top-8 merge of sorted-8 L and sorted-4 {s0..s3}
            L[4] = fmaxf(L[4], s3);
            L[5] = fmaxf(L[5], s2);
            L[6] = fmaxf(L[6], s1);
            L[7] = fmaxf(L[7], s0);
            BSTAGES(L)
        }
    }

    // quad merge across the 4 lanes of this row
#pragma unroll
    for (int mm = 16; mm <= 32; mm <<= 1) {
        float o[8], X[8];
#pragma unroll
        for (int t = 0; t < 8; ++t) o[t] = __shfl_xor(L[t], mm, 64);
#pragma unroll
        for (int t = 0; t < 8; ++t) X[t] = fmaxf(L[t], o[7 - t]);
        BSTAGES(X)
#pragma unroll
        for (int t = 0; t < 8; ++t) L[t] = X[t];
    }

    if (q == 0) {
        float* dst = tq + ((size_t)seg * NN + (row0 + n)) * 8;
#pragma unroll
        for (int t = 0; t < 8; ++t) dst[t] = L[t];
    }
}

// ---------------------------------------------------------------------------
// p15: tau[row] = 8th-largest value over the 8 per-segment sorted lists;
// zero cnt[row]. One thread per row.
// ---------------------------------------------------------------------------
__global__ __launch_bounds__(256) void p15_tau(const float* __restrict__ tq,
                                               float* __restrict__ tau,
                                               int* __restrict__ cnt)
{
    const int row = blockIdx.x * 256 + threadIdx.x;
    float hd[SEG]; int ix[SEG];
#pragma unroll
    for (int s = 0; s < SEG; ++s) { hd[s] = tq[((size_t)s * NN + row) * 8]; ix[s] = 0; }
    float tv = -INFINITY;
#pragma unroll
    for (int t = 0; t < 8; ++t) {
        float best = hd[0]; int bs = 0;
#pragma unroll
        for (int s = 1; s < SEG; ++s)
            if (hd[s] > best) { best = hd[s]; bs = s; }
        tv = best;
        ++ix[bs];
        hd[bs] = (ix[bs] < 8) ? tq[((size_t)bs * NN + row) * 8 + ix[bs]] : -INFINITY;
    }
    tau[row] = tv;
    cnt[row] = 0;
}

// ---------------------------------------------------------------------------
// p2: re-scan (bitwise-identical MFMA values) and append candidates with
// v >= tau[row] (>= 8 incl. self, <= 16 barring 9-way float ties). Gate
// opens rarely; body is tiny (atomicAdd + 2 stores).
// ---------------------------------------------------------------------------
__global__ __launch_bounds__(256, 4) void p2_emit(const ushort* __restrict__ PA1,
                                                  const ushort* __restrict__ PA2,
                                                  const ushort* __restrict__ PA3,
                                                  const ushort* __restrict__ PB1,
                                                  const ushort* __restrict__ PB2,
                                                  const float* __restrict__ tau,
                                                  int* __restrict__ cnt,
                                                  float* __restrict__ candv,
                                                  int* __restrict__ candj)
{
    __shared__ s8v lds[2048];

    const int tid  = threadIdx.x;
    const int lane = tid & 63;
    const int wv   = tid >> 6;
    const int seg  = blockIdx.x & (SEG - 1);
    const int row0 = (blockIdx.x >> 3) * 64 + wv * 16;
    const int n    = lane & 15;
    const int q    = lane >> 4;
    const int qs   = (q + ((n >> 1) & 3)) & 3;
    const int row  = row0 + n;

    const size_t ioff = ((size_t)row << 5) + (q << 3);
    const s8v i1 = *(const s8v*)(PA1 + ioff);
    const s8v i2 = *(const s8v*)(PA2 + ioff);
    const s8v i3 = *(const s8v*)(PA3 + ioff);
    const float tv = tau[row];

    for (int cc = 0; cc < NCH; ++cc) {
        __syncthreads();
#pragma unroll
        for (int it = 0; it < 8; ++it) {
            const int o  = it * 256 + tid;
            const int oo = o & 1023;
            const int c  = oo >> 2;
            const int qq = oo & 3;
            const int sw = (qq + ((c >> 1) & 3)) & 3;
            const ushort* src = (it < 4) ? PB1 : PB2;
            const int gcol = seg * SW + cc * CCOL + c;
            const s8v v = *(const s8v*)(src + ((size_t)gcol << 5) + (qq << 3));
            lds[((it < 4) ? 0 : 1024) + (c << 2) + sw] = v;
        }
        __syncthreads();

        const int base = (n << 2) + qs;
#pragma unroll 4
        for (int t = 0; t < TPC; ++t) {
            const s8v jb1 = lds[t * 64 + base];
            const s8v jb2 = lds[1024 + t * 64 + base];

            f4v acc = {0.f, 0.f, 0.f, 0.f};
            acc = __builtin_amdgcn_mfma_f32_16x16x32_bf16(jb1, i1, acc, 0, 0, 0);
            acc = __builtin_amdgcn_mfma_f32_16x16x32_bf16(jb2, i2, acc, 0, 0, 0);
            acc = __builtin_amdgcn_mfma_f32_16x16x32_bf16(jb1, i3, acc, 0, 0, 0);

            const float vm = fmaxf(fmaxf(acc[0], acc[1]), fmaxf(acc[2], acc[3]));
            if (__builtin_expect(vm >= tv, 0)) {
                const int jbase = seg * SW + cc * CCOL + t * 16 + (q << 2);
#pragma unroll
                for (int g = 0; g < 4; ++g) {
                    if (acc[g] >= tv) {
                        const int idx = atomicAdd(&cnt[row], 1);
                        if (idx < 16) {
                            candv[(size_t)row * 16 + idx] = acc[g];
                            candj[(size_t)row * 16 + idx] = jbase + g;
                        }
                    }
                }
            }
        }
    }
}

// ---------------------------------------------------------------------------
// p3: exact top-7 over <=16 candidates per row, (value desc, index asc);
// rank 0 = self, dropped; emit neighbor idx/val. One thread per row.
// ---------------------------------------------------------------------------
__global__ __launch_bounds__(256) void p3_select(const int* __restrict__ cnt,
                                                 const float* __restrict__ candv,
                                                 const int* __restrict__ candj,
                                                 int* __restrict__ nbr_idx,
                                                 float* __restrict__ nbr_val)
{
    const int row = blockIdx.x * 256 + threadIdx.x;
    const int c = min(cnt[row], 16);
    uint64_t keys[16];
    for (int i = 0; i < c; ++i) {
        const float v = candv[(size_t)row * 16 + i];
        const uint32_t j = (uint32_t)candj[(size_t)row * 16 + i];
        keys[i] = ((uint64_t)fflip(v) << 32) | (uint64_t)(~j);
    }
    for (int t = 0; t < 7; ++t) {
        uint64_t best = 0; int bi = 0;
        for (int i = 0; i < c; ++i)
            if (keys[i] > best) { best = keys[i]; bi = i; }
        keys[bi] = 0;
        if (t >= 1) {
            uint32_t u = (uint32_t)(best >> 32);
            u = (u & 0x80000000u) ? (u & 0x7fffffffu) : ~u;
            nbr_val[(size_t)row * KN + (t - 1)] = __uint_as_float(u);
            nbr_idx[(size_t)row * KN + (t - 1)] = (int)~(uint32_t)best;
        }
    }
}

// ---------------------------------------------------------------------------
// k3: zero-fill d_out — grid-stride, plain coherent float4 stores
// ---------------------------------------------------------------------------
__global__ __launch_bounds__(256) void k3_zero(float4* __restrict__ out)
{
    const size_t base = (size_t)blockIdx.x * 1024 + threadIdx.x;
    const float4 z = make_float4(0.f, 0.f, 0.f, 0.f);
#pragma unroll
    for (int qq = 0; qq < 4; ++qq)
        out[base + (size_t)qq * 256] = z;
}

// ---------------------------------------------------------------------------
// k4: rs[i] = row sums of symmetrized sparse matrix
// ---------------------------------------------------------------------------
__global__ __launch_bounds__(256) void k4_rowsum(const int* __restrict__ nbr_idx,
                                                 const float* __restrict__ nbr_val,
                                                 float* __restrict__ rs)
{
    const int e = blockIdx.x * 256 + threadIdx.x;
    const int i = e / KN;
    const int j = nbr_idx[e];
    const float v = nbr_val[e] * 0.5f;
    atomicAdd(&rs[i], v);
    atomicAdd(&rs[j], v);
}

// ---------------------------------------------------------------------------
// k5: scatter normalized values into pre-zeroed dense output
// ---------------------------------------------------------------------------
__global__ __launch_bounds__(256) void k5_scatter(const int* __restrict__ nbr_idx,
                                                  const float* __restrict__ nbr_val,
                                                  const float* __restrict__ rs,
                                                  float* __restrict__ out)
{
    const int e = blockIdx.x * 256 + threadIdx.x;
    const int i = e / KN;
    const int j = nbr_idx[e];
    const float v = nbr_val[e] * 0.5f;
    const float wi = v / (rs[i] + 1e-8f);
    const float wj = v / (rs[j] + 1e-8f);
    atomicAdd(out + (size_t)i * NN + j, wi);
    atomicAdd(out + (size_t)j * NN + i, wj);
}

// ---------------------------------------------------------------------------
extern "C" void kernel_launch(void* const* d_in, const int* in_sizes, int n_in,
                              void* d_out, int out_size, void* d_ws, size_t ws_size,
                              hipStream_t stream)
{
    const float* x = (const float*)d_in[0];   // 8192 x 256
    const float* W = (const float*)d_in[1];   // 16 x 256
    const float* b = (const float*)d_in[2];   // 16
    float* out = (float*)d_out;               // 8192 x 8192

    // workspace layout (~6 MB), all boundaries multiples of NN elements
    float* tq    = (float*)d_ws;                      // SEG*NN*8
    float* tau   = tq + (size_t)SEG * NN * 8;         // NN
    float* h     = tau + NN;                          // NN*HID
    float* rs    = h + (size_t)NN * HID;              // NN
    float* nv    = rs + NN;                           // NN*KN
    float* candv = nv + (size_t)NN * KN;              // NN*16
    int*   ni    = (int*)(candv + (size_t)NN * 16);   // NN*KN
    int*   candj = ni + (size_t)NN * KN;              // NN*16
    int*   cnt   = candj + (size_t)NN * 16;           // NN
    ushort* PA1  = (ushort*)(cnt + NN);               // NN*32 each
    ushort* PA2  = PA1 + (size_t)NN * 32;
    ushort* PA3  = PA2 + (size_t)NN * 32;
    ushort* PB1  = PA3 + (size_t)NN * 32;
    ushort* PB2  = PB1 + (size_t)NN * 32;

    k1_embed <<<NN / 4,            256, 0, stream>>>(x, W, b, h, rs);
    k1b_split<<<(NN * 32) / 256,   256, 0, stream>>>(h, PA1, PA2, PA3, PB1, PB2);
    p1_scan  <<<(NN / 64) * SEG,   256, 0, stream>>>(PA1, PA2, PA3, PB1, PB2, tq);
    p15_tau  <<<NN / 256,          256, 0, stream>>>(tq, tau, cnt);
    p2_emit  <<<(NN / 64) * SEG,   256, 0, stream>>>(PA1, PA2, PA3, PB1, PB2, tau, cnt, candv, candj);
    p3_select<<<NN / 256,          256, 0, stream>>>(cnt, candv, candj, ni, nv);
    k3_zero  <<<(int)(((size_t)NN * NN / 4) / 1024), 256, 0, stream>>>((float4*)out);
    k4_rowsum<<<(NN * KN) / 256,   256, 0, stream>>>(ni, nv, rs);
    k5_scatter<<<(NN * KN) / 256,  256, 0, stream>>>(ni, nv, rs, out);
}

// Round 14
// 321.902 us; speedup vs baseline: 1.9891x; 1.1411x over previous
//
#include <hip/hip_runtime.h>
#include <stdint.h>
#include <math.h>

#define NN   8192
#define IND  256
#define HID  16
#define KN   6
#define SEG  8          // col segments
#define SW   (NN/SEG)   // 1024 cols per segment
#define CCOL 256        // cols per LDS chunk
#define NCH  (SW/CCOL)  // 4 chunks per block
#define TPC  (CCOL/16)  // 16 tiles per chunk
#define ZPB  8192       // float4 zero-stores per block per pass (128 KB)

typedef short s8v  __attribute__((ext_vector_type(8)));
typedef float f4v  __attribute__((ext_vector_type(4)));

__device__ __forceinline__ uint32_t fflip(float f) {
    const uint32_t u = __float_as_uint(f);
    return (u & 0x80000000u) ? ~u : (u | 0x80000000u);
}

__device__ __forceinline__ uint32_t bf16_rne_bits(float x) {
    const uint32_t u = __float_as_uint(x);
    return (u + 0x7FFFu + ((u >> 16) & 1u)) & 0xFFFF0000u;
}

// ---------------------------------------------------------------------------
// k1: h[i] = normalize(x[i] @ W^T + b), also zero rs[i].
// ---------------------------------------------------------------------------
__global__ __launch_bounds__(256) void k1_embed(const float* __restrict__ x,
                                                const float* __restrict__ W,
                                                const float* __restrict__ b,
                                                float* __restrict__ h,
                                                float* __restrict__ rs)
{
    const int lane = threadIdx.x & 63;
    const int wv   = threadIdx.x >> 6;
    const int row  = blockIdx.x * 4 + wv;

    const float4 xv = *(const float4*)(x + (size_t)row * IND + lane * 4);

    float acc[HID];
#pragma unroll
    for (int k = 0; k < HID; ++k) {
        const float4 wv4 = *(const float4*)(W + (size_t)k * IND + lane * 4);
        float v = xv.x * wv4.x + xv.y * wv4.y + xv.z * wv4.z + xv.w * wv4.w;
#pragma unroll
        for (int m = 32; m >= 1; m >>= 1) v += __shfl_xor(v, m, 64);
        acc[k] = v;
    }

    if (lane == 0) {
        float hv[HID];
        float ss = 0.f;
#pragma unroll
        for (int k = 0; k < HID; ++k) { hv[k] = acc[k] + b[k]; ss += hv[k] * hv[k]; }
        const float nrm = fmaxf(sqrtf(ss), 1e-12f);
#pragma unroll
        for (int k = 0; k < HID; ++k) hv[k] = hv[k] / nrm;
        float4* hp = (float4*)(h + (size_t)row * HID);
        hp[0] = make_float4(hv[0],  hv[1],  hv[2],  hv[3]);
        hp[1] = make_float4(hv[4],  hv[5],  hv[6],  hv[7]);
        hp[2] = make_float4(hv[8],  hv[9],  hv[10], hv[11]);
        hp[3] = make_float4(hv[12], hv[13], hv[14], hv[15]);
        rs[row] = 0.f;
    }
}

// ---------------------------------------------------------------------------
// k1b: 3 exact bf16 limbs; 5 K=32 packings (verified R8-R13):
// PA1=[hi|hi] PA2=[mid|hi] PA3=[lo|mid] (i side), PB1=[hi|mid] PB2=[hi|lo]
// (j side). mfma(PB1,PA1)+mfma(PB2,PA2)+mfma(PB1,PA3) -> ~6e-8 per-sim err.
// ---------------------------------------------------------------------------
__global__ __launch_bounds__(256) void k1b_split(const float* __restrict__ h,
                                                 ushort* __restrict__ PA1,
                                                 ushort* __restrict__ PA2,
                                                 ushort* __restrict__ PA3,
                                                 ushort* __restrict__ PB1,
                                                 ushort* __restrict__ PB2)
{
    const int t   = blockIdx.x * 256 + threadIdx.x;   // < NN*32
    const int row = t >> 5;
    const int s   = t & 31;
    const int k   = s & 15;

    const float x = h[(size_t)row * HID + k];
    const uint32_t hb = bf16_rne_bits(x);
    const float r1 = x - __uint_as_float(hb);
    const uint32_t mb = bf16_rne_bits(r1);
    const float r2 = r1 - __uint_as_float(mb);
    const uint32_t lb = bf16_rne_bits(r2);
    const ushort hi = (ushort)(hb >> 16);
    const ushort mi = (ushort)(mb >> 16);
    const ushort lo = (ushort)(lb >> 16);

    const bool f = (s < 16);
    PA1[t] = hi;
    PA2[t] = f ? mi : hi;
    PA3[t] = f ? lo : mi;
    PB1[t] = f ? hi : mi;
    PB2[t] = f ? hi : lo;
}

// branch-free comparators (desc)
#define CSWPF(X,i,j) { const float _h = fmaxf(X[i], X[j]); const float _l = fminf(X[i], X[j]); X[i] = _h; X[j] = _l; }
#define CSWPV(a,b)   { const float _h = fmaxf(a, b); const float _l = fminf(a, b); a = _h; b = _l; }
#define BSTAGES(X) CSWPF(X,0,4) CSWPF(X,1,5) CSWPF(X,2,6) CSWPF(X,3,7) \
                   CSWPF(X,0,2) CSWPF(X,1,3) CSWPF(X,4,6) CSWPF(X,5,7) \
                   CSWPF(X,0,1) CSWPF(X,2,3) CSWPF(X,4,5) CSWPF(X,6,7)

// ---------------------------------------------------------------------------
// p1: branch-free value scan + fused zero-fill of out[0..half). Per tile:
// 2 swizzled ds_read_b128 + 3-limb MFMA + sort-4 + bitonic top-8 merge into
// one per-lane list (38 VALU, no branches). The 8 float4 zero-stores per
// chunk ride the idle VMEM pipe under the VALU-bound tile loop (was k3,
// 46 us of serialized HBM write). Epilogue: 2-step shfl quad merge.
// ---------------------------------------------------------------------------
__global__ __launch_bounds__(256, 4) void p1_scan(const ushort* __restrict__ PA1,
                                                  const ushort* __restrict__ PA2,
                                                  const ushort* __restrict__ PA3,
                                                  const ushort* __restrict__ PB1,
                                                  const ushort* __restrict__ PB2,
                                                  float* __restrict__ tq,
                                                  float4* __restrict__ outz)
{
    __shared__ s8v lds[2048];   // 32 KB: PB1 chunk | PB2 chunk

    const int tid  = threadIdx.x;
    const int lane = tid & 63;
    const int wv   = tid >> 6;
    const int seg  = blockIdx.x & (SEG - 1);
    const int row0 = (blockIdx.x >> 3) * 64 + wv * 16;
    const int n    = lane & 15;
    const int q    = lane >> 4;
    const int qs   = (q + ((n >> 1) & 3)) & 3;

    const size_t ioff = ((size_t)(row0 + n) << 5) + (q << 3);
    const s8v i1 = *(const s8v*)(PA1 + ioff);
    const s8v i2 = *(const s8v*)(PA2 + ioff);
    const s8v i3 = *(const s8v*)(PA3 + ioff);

    const float4 zf = make_float4(0.f, 0.f, 0.f, 0.f);

    float L[8];
#pragma unroll
    for (int t = 0; t < 8; ++t) L[t] = -INFINITY;

    for (int cc = 0; cc < NCH; ++cc) {
        __syncthreads();
#pragma unroll
        for (int it = 0; it < 8; ++it) {
            const int o  = it * 256 + tid;
            const int oo = o & 1023;
            const int c  = oo >> 2;
            const int qq = oo & 3;
            const int sw = (qq + ((c >> 1) & 3)) & 3;
            const ushort* src = (it < 4) ? PB1 : PB2;
            const int gcol = seg * SW + cc * CCOL + c;
            const s8v v = *(const s8v*)(src + ((size_t)gcol << 5) + (qq << 3));
            lds[((it < 4) ? 0 : 1024) + (c << 2) + sw] = v;
        }
        __syncthreads();

        // fused zero-fill: 8 stores/thread/chunk, drain under the tile loop
        {
            const size_t zb = (size_t)blockIdx.x * ZPB + (size_t)cc * 2048 + tid;
#pragma unroll
            for (int z = 0; z < 8; ++z)
                outz[zb + z * 256] = zf;
        }

        const int base = (n << 2) + qs;
#pragma unroll 4
        for (int t = 0; t < TPC; ++t) {
            const s8v jb1 = lds[t * 64 + base];
            const s8v jb2 = lds[1024 + t * 64 + base];

            f4v acc = {0.f, 0.f, 0.f, 0.f};
            acc = __builtin_amdgcn_mfma_f32_16x16x32_bf16(jb1, i1, acc, 0, 0, 0);
            acc = __builtin_amdgcn_mfma_f32_16x16x32_bf16(jb2, i2, acc, 0, 0, 0);
            acc = __builtin_amdgcn_mfma_f32_16x16x32_bf16(jb1, i3, acc, 0, 0, 0);

            // sort 4 values desc (5 comparators)
            float s0 = acc[0], s1 = acc[1], s2 = acc[2], s3 = acc[3];
            CSWPV(s0, s1) CSWPV(s2, s3) CSWPV(s0, s2) CSWPV(s1, s3) CSWPV(s1, s2)

            // bitonic top-8 merge of sorted-8 L and sorted-4 {s0..s3}
            L[4] = fmaxf(L[4], s3);
            L[5] = fmaxf(L[5], s2);
            L[6] = fmaxf(L[6], s1);
            L[7] = fmaxf(L[7], s0);
            BSTAGES(L)
        }
    }

    // quad merge across the 4 lanes of this row
#pragma unroll
    for (int mm = 16; mm <= 32; mm <<= 1) {
        float o[8], X[8];
#pragma unroll
        for (int t = 0; t < 8; ++t) o[t] = __shfl_xor(L[t], mm, 64);
#pragma unroll
        for (int t = 0; t < 8; ++t) X[t] = fmaxf(L[t], o[7 - t]);
        BSTAGES(X)
#pragma unroll
        for (int t = 0; t < 8; ++t) L[t] = X[t];
    }

    if (q == 0) {
        float* dst = tq + ((size_t)seg * NN + (row0 + n)) * 8;
#pragma unroll
        for (int t = 0; t < 8; ++t) dst[t] = L[t];
    }
}

// ---------------------------------------------------------------------------
// p15: tau[row] = 8th-largest value over the 8 per-segment sorted lists;
// zero cnt[row]. One thread per row.
// ---------------------------------------------------------------------------
__global__ __launch_bounds__(256) void p15_tau(const float* __restrict__ tq,
                                               float* __restrict__ tau,
                                               int* __restrict__ cnt)
{
    const int row = blockIdx.x * 256 + threadIdx.x;
    float hd[SEG]; int ix[SEG];
#pragma unroll
    for (int s = 0; s < SEG; ++s) { hd[s] = tq[((size_t)s * NN + row) * 8]; ix[s] = 0; }
    float tv = -INFINITY;
#pragma unroll
    for (int t = 0; t < 8; ++t) {
        float best = hd[0]; int bs = 0;
#pragma unroll
        for (int s = 1; s < SEG; ++s)
            if (hd[s] > best) { best = hd[s]; bs = s; }
        tv = best;
        ++ix[bs];
        hd[bs] = (ix[bs] < 8) ? tq[((size_t)bs * NN + row) * 8 + ix[bs]] : -INFINITY;
    }
    tau[row] = tv;
    cnt[row] = 0;
}

// ---------------------------------------------------------------------------
// p2: re-scan (bitwise-identical MFMA values), append candidates with
// v >= tau[row], and zero-fill out[half..end) on the idle VMEM pipe.
// ---------------------------------------------------------------------------
__global__ __launch_bounds__(256, 4) void p2_emit(const ushort* __restrict__ PA1,
                                                  const ushort* __restrict__ PA2,
                                                  const ushort* __restrict__ PA3,
                                                  const ushort* __restrict__ PB1,
                                                  const ushort* __restrict__ PB2,
                                                  const float* __restrict__ tau,
                                                  int* __restrict__ cnt,
                                                  float* __restrict__ candv,
                                                  int* __restrict__ candj,
                                                  float4* __restrict__ outz)
{
    __shared__ s8v lds[2048];

    const int tid  = threadIdx.x;
    const int lane = tid & 63;
    const int wv   = tid >> 6;
    const int seg  = blockIdx.x & (SEG - 1);
    const int row0 = (blockIdx.x >> 3) * 64 + wv * 16;
    const int n    = lane & 15;
    const int q    = lane >> 4;
    const int qs   = (q + ((n >> 1) & 3)) & 3;
    const int row  = row0 + n;

    const size_t ioff = ((size_t)row << 5) + (q << 3);
    const s8v i1 = *(const s8v*)(PA1 + ioff);
    const s8v i2 = *(const s8v*)(PA2 + ioff);
    const s8v i3 = *(const s8v*)(PA3 + ioff);
    const float tv = tau[row];

    const float4 zf = make_float4(0.f, 0.f, 0.f, 0.f);

    for (int cc = 0; cc < NCH; ++cc) {
        __syncthreads();
#pragma unroll
        for (int it = 0; it < 8; ++it) {
            const int o  = it * 256 + tid;
            const int oo = o & 1023;
            const int c  = oo >> 2;
            const int qq = oo & 3;
            const int sw = (qq + ((c >> 1) & 3)) & 3;
            const ushort* src = (it < 4) ? PB1 : PB2;
            const int gcol = seg * SW + cc * CCOL + c;
            const s8v v = *(const s8v*)(src + ((size_t)gcol << 5) + (qq << 3));
            lds[((it < 4) ? 0 : 1024) + (c << 2) + sw] = v;
        }
        __syncthreads();

        // fused zero-fill (second half of out)
        {
            const size_t zb = (size_t)(NN / 8) * NN / 2 +
                              (size_t)blockIdx.x * ZPB + (size_t)cc * 2048 + tid;
#pragma unroll
            for (int z = 0; z < 8; ++z)
                outz[zb + z * 256] = zf;
        }

        const int base = (n << 2) + qs;
#pragma unroll 4
        for (int t = 0; t < TPC; ++t) {
            const s8v jb1 = lds[t * 64 + base];
            const s8v jb2 = lds[1024 + t * 64 + base];

            f4v acc = {0.f, 0.f, 0.f, 0.f};
            acc = __builtin_amdgcn_mfma_f32_16x16x32_bf16(jb1, i1, acc, 0, 0, 0);
            acc = __builtin_amdgcn_mfma_f32_16x16x32_bf16(jb2, i2, acc, 0, 0, 0);
            acc = __builtin_amdgcn_mfma_f32_16x16x32_bf16(jb1, i3, acc, 0, 0, 0);

            const float vm = fmaxf(fmaxf(acc[0], acc[1]), fmaxf(acc[2], acc[3]));
            if (__builtin_expect(vm >= tv, 0)) {
                const int jbase = seg * SW + cc * CCOL + t * 16 + (q << 2);
#pragma unroll
                for (int g = 0; g < 4; ++g) {
                    if (acc[g] >= tv) {
                        const int idx = atomicAdd(&cnt[row], 1);
                        if (idx < 16) {
                            candv[(size_t)row * 16 + idx] = acc[g];
                            candj[(size_t)row * 16 + idx] = jbase + g;
                        }
                    }
                }
            }
        }
    }
}

// ---------------------------------------------------------------------------
// p3: exact top-7 over <=16 candidates per row, (value desc, index asc);
// rank 0 = self, dropped; emit neighbor idx/val. One thread per row.
// ---------------------------------------------------------------------------
__global__ __launch_bounds__(256) void p3_select(const int* __restrict__ cnt,
                                                 const float* __restrict__ candv,
                                                 const int* __restrict__ candj,
                                                 int* __restrict__ nbr_idx,
                                                 float* __restrict__ nbr_val)
{
    const int row = blockIdx.x * 256 + threadIdx.x;
    const int c = min(cnt[row], 16);
    uint64_t keys[16];
    for (int i = 0; i < c; ++i) {
        const float v = candv[(size_t)row * 16 + i];
        const uint32_t j = (uint32_t)candj[(size_t)row * 16 + i];
        keys[i] = ((uint64_t)fflip(v) << 32) | (uint64_t)(~j);
    }
    for (int t = 0; t < 7; ++t) {
        uint64_t best = 0; int bi = 0;
        for (int i = 0; i < c; ++i)
            if (keys[i] > best) { best = keys[i]; bi = i; }
        keys[bi] = 0;
        if (t >= 1) {
            uint32_t u = (uint32_t)(best >> 32);
            u = (u & 0x80000000u) ? (u & 0x7fffffffu) : ~u;
            nbr_val[(size_t)row * KN + (t - 1)] = __uint_as_float(u);
            nbr_idx[(size_t)row * KN + (t - 1)] = (int)~(uint32_t)best;
        }
    }
}

// ---------------------------------------------------------------------------
// k4: rs[i] = row sums of symmetrized sparse matrix
// ---------------------------------------------------------------------------
__global__ __launch_bounds__(256) void k4_rowsum(const int* __restrict__ nbr_idx,
                                                 const float* __restrict__ nbr_val,
                                                 float* __restrict__ rs)
{
    const int e = blockIdx.x * 256 + threadIdx.x;
    const int i = e / KN;
    const int j = nbr_idx[e];
    const float v = nbr_val[e] * 0.5f;
    atomicAdd(&rs[i], v);
    atomicAdd(&rs[j], v);
}

// ---------------------------------------------------------------------------
// k5: scatter normalized values into pre-zeroed dense output
// ---------------------------------------------------------------------------
__global__ __launch_bounds__(256) void k5_scatter(const int* __restrict__ nbr_idx,
                                                  const float* __restrict__ nbr_val,
                                                  const float* __restrict__ rs,
                                                  float* __restrict__ out)
{
    const int e = blockIdx.x * 256 + threadIdx.x;
    const int i = e / KN;
    const int j = nbr_idx[e];
    const float v = nbr_val[e] * 0.5f;
    const float wi = v / (rs[i] + 1e-8f);
    const float wj = v / (rs[j] + 1e-8f);
    atomicAdd(out + (size_t)i * NN + j, wi);
    atomicAdd(out + (size_t)j * NN + i, wj);
}

// ---------------------------------------------------------------------------
extern "C" void kernel_launch(void* const* d_in, const int* in_sizes, int n_in,
                              void* d_out, int out_size, void* d_ws, size_t ws_size,
                              hipStream_t stream)
{
    const float* x = (const float*)d_in[0];   // 8192 x 256
    const float* W = (const float*)d_in[1];   // 16 x 256
    const float* b = (const float*)d_in[2];   // 16
    float* out = (float*)d_out;               // 8192 x 8192

    // workspace layout (~6 MB), all boundaries multiples of NN elements
    float* tq    = (float*)d_ws;                      // SEG*NN*8
    float* tau   = tq + (size_t)SEG * NN * 8;         // NN
    float* h     = tau + NN;                          // NN*HID
    float* rs    = h + (size_t)NN * HID;              // NN
    float* nv    = rs + NN;                           // NN*KN
    float* candv = nv + (size_t)NN * KN;              // NN*16
    int*   ni    = (int*)(candv + (size_t)NN * 16);   // NN*KN
    int*   candj = ni + (size_t)NN * KN;              // NN*16
    int*   cnt   = candj + (size_t)NN * 16;           // NN
    ushort* PA1  = (ushort*)(cnt + NN);               // NN*32 each
    ushort* PA2  = PA1 + (size_t)NN * 32;
    ushort* PA3  = PA2 + (size_t)NN * 32;
    ushort* PB1  = PA3 + (size_t)NN * 32;
    ushort* PB2  = PB1 + (size_t)NN * 32;

    k1_embed <<<NN / 4,            256, 0, stream>>>(x, W, b, h, rs);
    k1b_split<<<(NN * 32) / 256,   256, 0, stream>>>(h, PA1, PA2, PA3, PB1, PB2);
    p1_scan  <<<(NN / 64) * SEG,   256, 0, stream>>>(PA1, PA2, PA3, PB1, PB2, tq, (float4*)out);
    p15_tau  <<<NN / 256,          256, 0, stream>>>(tq, tau, cnt);
    p2_emit  <<<(NN / 64) * SEG,   256, 0, stream>>>(PA1, PA2, PA3, PB1, PB2, tau, cnt, candv, candj, (float4*)out);
    p3_select<<<NN / 256,          256, 0, stream>>>(cnt, candv, candj, ni, nv);
    k4_rowsum<<<(NN * KN) / 256,   256, 0, stream>>>(ni, nv, rs);
    k5_scatter<<<(NN * KN) / 256,  256, 0, stream>>>(ni, nv, rs, out);
}